// Round 5
// baseline (876.033 us; speedup 1.0000x reference)
//
#include <hip/hip_runtime.h>
#include <hip/hip_bf16.h>
#include <cmath>

#define NB   32
#define SOUT 2048
#define SIN  512
#define LOG2E 1.4426950408889634f

typedef __attribute__((ext_vector_type(8))) short bhalf8;   // 8 bf16 (4 VGPRs)
typedef __attribute__((ext_vector_type(4))) float f32x4;

__device__ inline ushort f2b(float x) {                     // f32 -> bf16 RNE
  union { float f; unsigned u; } v; v.f = x;
  unsigned r = v.u + 0x7FFFu + ((v.u >> 16) & 1u);
  return (ushort)(r >> 16);
}
__device__ inline ushort f2b_trunc(float x) {               // f32 -> bf16 trunc (x>0)
  union { float f; unsigned u; } v; v.f = x;
  return (ushort)(v.u >> 16);
}
__device__ inline float b2f(ushort u) {
  union { unsigned u; float f; } v; v.u = ((unsigned)u) << 16;
  return v.f;
}

__device__ inline void gload16(const void* g, void* l) {    // async global->LDS, 16B/lane
  __builtin_amdgcn_global_load_lds(
      (const __attribute__((address_space(1))) void*)g,
      (__attribute__((address_space(3))) void*)l, 16, 0, 0);
}

// ---------------------------------------------------------------------------
// pts
// ---------------------------------------------------------------------------
__global__ void pts_kernel(const int* __restrict__ mArr, const int* __restrict__ nArr,
                           float* __restrict__ pts) {
  int k = blockIdx.x * blockDim.x + threadIdx.x;
  if (k >= SOUT) return;
  int m = mArr[0], n = nArr[0];
  int b = k % m, a = k / m;
  int ixb = (int)rint(45.0 * (double)b / (double)(m - 1));
  int iya = (int)rint(45.0 * (double)a / (double)(n - 1));
  const float step = 0.6f / 45.0f;
  pts[2 * k + 0] = -0.3f + step * (float)iya;
  pts[2 * k + 1] = -0.3f + step * (float)ixb;
}

// ---------------------------------------------------------------------------
// wconv: transpose-convert weights W[K,N] f32 -> Wt[N,K] bf16; which==6 builds
// the concatenated h|l bias (float).
// ---------------------------------------------------------------------------
__global__ __launch_bounds__(256) void wconv_kernel(
    const float* __restrict__ Wh, const float* __restrict__ Wl,
    const float* __restrict__ Wg, const float* __restrict__ Wf,
    const float* __restrict__ Wd1, const float* __restrict__ Wd2,
    const float* __restrict__ bh, const float* __restrict__ bl,
    ushort* __restrict__ dst, float* __restrict__ fbias) {
  const int which = blockIdx.y;
  if (which == 6) {
    int idx = blockIdx.x * 256 + threadIdx.x;
    if (idx < 128) fbias[idx] = idx < 64 ? bh[idx] : bl[idx - 64];
    return;
  }
  const float* src; int K, N; long off;
  switch (which) {
    case 0: src = Wh;  K = 256; N = 64;  off = 0;      break;
    case 1: src = Wl;  K = 256; N = 64;  off = 16384;  break;
    case 2: src = Wg;  K = 256; N = 256; off = 32768;  break;
    case 3: src = Wf;  K = 256; N = 128; off = 98304;  break;
    case 4: src = Wd1; K = 512; N = 256; off = 131072; break;
    default:src = Wd2; K = 256; N = 128; off = 262144; break;
  }
  int idx = blockIdx.x * 256 + threadIdx.x;
  if (idx >= K * N) return;
  int n = idx / K, k = idx - n * K;
  dst[off + idx] = f2b(src[(long)k * N + n]);
}

// ---------------------------------------------------------------------------
// qc builder -> qcb bf16 only
// ---------------------------------------------------------------------------
__global__ __launch_bounds__(128) void qc_kernel(
    const float* __restrict__ q, const float* __restrict__ pts,
    const float* __restrict__ Wup, const float* __restrict__ bup,
    ushort* __restrict__ qcb) {
  __shared__ float xs[16][132];
  int tid = threadIdx.x;
  long row0 = (long)blockIdx.x * 16;
  for (int r = 0; r < 16; ++r) {
    long row = row0 + r;
    int b = (int)(row >> 11);
    int i = (int)(row & 2047);
    xs[r][tid] = q[((long)b * SIN + (i & 511)) * 128 + tid];
    if (tid < 2) xs[r][128 + tid] = pts[2 * i + tid];
  }
  __syncthreads();
  float acc[16];
#pragma unroll
  for (int r = 0; r < 16; ++r) acc[r] = 0.f;
  for (int k = 0; k < 130; ++k) {
    float w = Wup[k * 128 + tid];
#pragma unroll
    for (int r = 0; r < 16; ++r) acc[r] += xs[r][k] * w;
  }
  float bb = bup[tid];
#pragma unroll
  for (int r = 0; r < 16; ++r) {
    long row = row0 + r;
    qcb[row * 256 + tid] = f2b(xs[r][tid]);
    qcb[row * 256 + 128 + tid] = f2b(fmaxf(acc[r] + bb, 0.f));
  }
}

// ---------------------------------------------------------------------------
// MFMA bf16 GEMM: acc = A[M,K] @ Wt[N,K]^T + bias, relu, epilogue by MODE.
//   MODE 0: bf16 row-major out
//   MODE 1: bf16 per-batch transposed gt [b][256][2048]
//   MODE 2: f32 out2 + bf16 outv
//   MODE 3: f32 outv = aux - relu(acc)
//   MODE 4: f32 outv = relu(acc) + aux
//   MODE 5: bf16 row-major out (N=128), cols>=64 scaled by LOG2E  (h|l merged)
// ---------------------------------------------------------------------------
template <int MODE>
__global__ __launch_bounds__(256) void mgemm(
    const ushort* __restrict__ A, const ushort* __restrict__ Wt,
    const float* __restrict__ bias, void* __restrict__ outv,
    float* __restrict__ out2, const float* __restrict__ aux,
    int M, int N, int K) {
  __shared__ alignas(16) ushort As[128 * 64];
  __shared__ alignas(16) ushort Bs[64 * 64];
  const int tid = threadIdx.x;
  const int w = tid >> 6, lane = tid & 63, g = lane >> 4, c = lane & 15;
  const int wm = w >> 1, wn = w & 1;
  const long row0 = (long)blockIdx.y * 128;
  const int col0 = blockIdx.x * 64;
  const long Astride = (long)K * 2;
  const char* Ab = (const char*)A;
  const char* Wb = (const char*)Wt;

  f32x4 acc[4][2];
#pragma unroll
  for (int i = 0; i < 4; ++i)
#pragma unroll
    for (int j = 0; j < 2; ++j) acc[i][j] = (f32x4){0.f, 0.f, 0.f, 0.f};

  for (int k0 = 0; k0 < K; k0 += 64) {
#pragma unroll
    for (int it = 0; it < 4; ++it) {
      int o = it * 4096 + w * 1024 + lane * 16;
      int row = o >> 7, cb = o & 127;
      gload16(Ab + (row0 + row) * Astride + k0 * 2 + (cb ^ ((row & 7) << 4)),
              (char*)As + it * 4096 + w * 1024);
    }
#pragma unroll
    for (int it = 0; it < 2; ++it) {
      int o = it * 4096 + w * 1024 + lane * 16;
      int row = o >> 7, cb = o & 127;
      gload16(Wb + (long)(col0 + row) * Astride + k0 * 2 + (cb ^ ((row & 7) << 4)),
              (char*)Bs + it * 4096 + w * 1024);
    }
    __syncthreads();
#pragma unroll
    for (int koff = 0; koff < 2; ++koff) {
      bhalf8 a[4], bfr[2];
#pragma unroll
      for (int mi = 0; mi < 4; ++mi) {
        int row = 64 * wm + 16 * mi + c;
        a[mi] = *(const bhalf8*)((const char*)As + row * 128 +
                                 ((16 * g + 64 * koff) ^ ((row & 7) << 4)));
      }
#pragma unroll
      for (int ni = 0; ni < 2; ++ni) {
        int row = 32 * wn + 16 * ni + c;
        bfr[ni] = *(const bhalf8*)((const char*)Bs + row * 128 +
                                   ((16 * g + 64 * koff) ^ ((row & 7) << 4)));
      }
#pragma unroll
      for (int mi = 0; mi < 4; ++mi)
#pragma unroll
        for (int ni = 0; ni < 2; ++ni)
          acc[mi][ni] = __builtin_amdgcn_mfma_f32_16x16x32_bf16(a[mi], bfr[ni], acc[mi][ni], 0, 0, 0);
    }
    __syncthreads();
  }

#pragma unroll
  for (int ni = 0; ni < 2; ++ni) {
    int n = col0 + 32 * wn + 16 * ni + c;
    float bn = bias[n];
#pragma unroll
    for (int mi = 0; mi < 4; ++mi) {
      long m0 = row0 + 64 * wm + 16 * mi + 4 * g;
      float v[4];
#pragma unroll
      for (int r = 0; r < 4; ++r) v[r] = fmaxf(acc[mi][ni][r] + bn, 0.f);
      if (MODE == 0) {
        ushort* O = (ushort*)outv;
#pragma unroll
        for (int r = 0; r < 4; ++r) O[(m0 + r) * N + n] = f2b(v[r]);
      } else if (MODE == 5) {
        ushort* O = (ushort*)outv;
        float sc = (n >= 64) ? LOG2E : 1.0f;
#pragma unroll
        for (int r = 0; r < 4; ++r) O[(m0 + r) * 128 + n] = f2b(v[r] * sc);
      } else if (MODE == 1) {
        int bb = (int)(m0 >> 11);
        int ml = (int)(m0 & 2047);
        ushort4 u4;
        u4.x = f2b(v[0]); u4.y = f2b(v[1]); u4.z = f2b(v[2]); u4.w = f2b(v[3]);
        *(ushort4*)((ushort*)outv + ((long)bb * 256 + n) * 2048 + ml) = u4;
      } else if (MODE == 2) {
        ushort* O = (ushort*)outv;
#pragma unroll
        for (int r = 0; r < 4; ++r) {
          out2[(m0 + r) * N + n] = v[r];
          O[(m0 + r) * N + n] = f2b(v[r]);
        }
      } else if (MODE == 3) {
        float* O = (float*)outv;
#pragma unroll
        for (int r = 0; r < 4; ++r) O[(m0 + r) * N + n] = aux[(m0 + r) * N + n] - v[r];
      } else {
        float* O = (float*)outv;
#pragma unroll
        for (int r = 0; r < 4; ++r) O[(m0 + r) * N + n] = v[r] + aux[(m0 + r) * N + n];
      }
    }
  }
}

// ---------------------------------------------------------------------------
// MFMA flash attention v5 (latency-hiding):
//   qcb[b,n,:] = bf16( qcb[b,n,:] + softmax_m(l[n]·h[m]) @ g )
// hl bf16 [b][2048][128] (cols 0:64=h, 64:128=l*log2e); gt bf16 [b][256][2048].
// H tile staged in LDS (double-buffered, prefetched 1 iter ahead via
// global_load_lds, drained at existing barriers); G fragments register
// double-buffered (issued 1 iter ahead, hidden under QK+softmax).
// ---------------------------------------------------------------------------
__global__ __launch_bounds__(256) void attn_kernel(
    const ushort* __restrict__ hl, const ushort* __restrict__ gtm,
    ushort* __restrict__ qcb) {
  __shared__ alignas(16) ushort Ht[2][64 * 64];  // swizzled, 8KB each
  __shared__ alignas(16) ushort Pt[64 * 72];
  __shared__ alignas(16) float rowscale[64];
  __shared__ int okf[4];

  const int tid = threadIdx.x;
  const int w = tid >> 6, lane = tid & 63, g = lane >> 4, c = lane & 15;
  const int bid = blockIdx.x;
  const int wg = (bid & 7) * 128 + (bid >> 3);   // XCD-contiguous remap (1024%8==0)
  const int b = wg >> 5, nb = wg & 31;
  const float THR = 11.0f;                        // log2 units

  // L (query, pre-scaled) fragments: rows 16w+c, k = 8g + 32s, cols 64..127
  const ushort* lrow = hl + ((long)b * SOUT + nb * 64 + 16 * w + c) * 128 + 64 + 8 * g;
  bhalf8 la[2];
  la[0] = *(const bhalf8*)(lrow);
  la[1] = *(const bhalf8*)(lrow + 32);

  bhalf8 ones;
#pragma unroll
  for (int i = 0; i < 8; ++i) ones[i] = (short)0x3F80;      // bf16 1.0

  float mold[4];
#pragma unroll
  for (int r = 0; r < 4; ++r) mold[r] = -INFINITY;
  f32x4 oacc[4][4], sumacc[4];
#pragma unroll
  for (int i = 0; i < 4; ++i) {
    sumacc[i] = (f32x4){0.f, 0.f, 0.f, 0.f};
#pragma unroll
    for (int t = 0; t < 4; ++t) oacc[i][t] = (f32x4){0.f, 0.f, 0.f, 0.f};
  }

  const char* hlbase = (const char*)(hl + (long)b * SOUT * 128);
  const ushort* gbase0 = gtm + ((long)b * 256 + 64 * w + c) * 2048 + 8 * g;

  // ---- prologue: stage H[0] into Ht[0]; load G[0] fragments ----
#pragma unroll
  for (int it = 0; it < 2; ++it) {
    int o = it * 4096 + w * 1024 + lane * 16;
    int row = o >> 7, cb = o & 127;
    gload16(hlbase + row * 256 + (cb ^ ((row & 7) << 4)),
            (char*)Ht[0] + it * 4096 + w * 1024);
  }
  bhalf8 gcur[2][4];
#pragma unroll
  for (int s2 = 0; s2 < 2; ++s2)
#pragma unroll
    for (int t = 0; t < 4; ++t)
      gcur[s2][t] = *(const bhalf8*)(gbase0 + (long)t * 16 * 2048 + 32 * s2);
  __syncthreads();  // Ht[0] resident (vmcnt drained by compiler)

  for (int mb = 0; mb < 32; ++mb) {
    // ---- prefetch next H tile (LDS dbuf) + next G fragments (regs) ----
    bhalf8 gnxt[2][4];
    if (mb < 31) {
      const char* hnext = hlbase + (long)(mb + 1) * 64 * 256;
#pragma unroll
      for (int it = 0; it < 2; ++it) {
        int o = it * 4096 + w * 1024 + lane * 16;
        int row = o >> 7, cb = o & 127;
        gload16(hnext + row * 256 + (cb ^ ((row & 7) << 4)),
                (char*)Ht[(mb + 1) & 1] + it * 4096 + w * 1024);
      }
      const ushort* gn = gbase0 + (mb + 1) * 64;
#pragma unroll
      for (int s2 = 0; s2 < 2; ++s2)
#pragma unroll
        for (int t = 0; t < 4; ++t)
          gnxt[s2][t] = *(const bhalf8*)(gn + (long)t * 16 * 2048 + 32 * s2);
    }

    // ---- QK^T from Ht[cur] (log2-domain scores) ----
    const char* hcur = (const char*)Ht[mb & 1];
    f32x4 sacc[4];
#pragma unroll
    for (int j = 0; j < 4; ++j) sacc[j] = (f32x4){0.f, 0.f, 0.f, 0.f};
#pragma unroll
    for (int j = 0; j < 4; ++j) {
      int row = 16 * j + c;
#pragma unroll
      for (int s = 0; s < 2; ++s) {
        bhalf8 hb = *(const bhalf8*)(hcur + row * 128 +
                                     ((16 * g + 64 * s) ^ ((c & 7) << 4)));
        sacc[j] = __builtin_amdgcn_mfma_f32_16x16x32_bf16(la[s], hb, sacc[j], 0, 0, 0);
      }
    }

    // ---- row max (rows 16w+4g+r) ----
    float mloc[4], mnew[4];
#pragma unroll
    for (int r = 0; r < 4; ++r)
      mloc[r] = fmaxf(fmaxf(sacc[0][r], sacc[1][r]), fmaxf(sacc[2][r], sacc[3][r]));
#pragma unroll
    for (int off = 1; off < 16; off <<= 1)
#pragma unroll
      for (int r = 0; r < 4; ++r)
        mloc[r] = fmaxf(mloc[r], __shfl_xor(mloc[r], off));
    int okl = 1;
#pragma unroll
    for (int r = 0; r < 4; ++r) {
      mnew[r] = fmaxf(mold[r], mloc[r]);
      okl &= (mloc[r] <= mold[r] + THR) ? 1 : 0;
    }
    int okw = __all(okl);
    if (lane == 0) okf[w] = okw;
    __syncthreads();                       // b1: WAR for Pt/rowscale; drains H prefetch
    int ok = okf[0] & okf[1] & okf[2] & okf[3];

    if (!ok) {
      float scl[4];
#pragma unroll
      for (int r = 0; r < 4; ++r) {
        scl[r] = exp2f(mold[r] - mnew[r]); // first iter: exp2(-inf)=0
        mold[r] = mnew[r];
      }
      if (c == 0) {
        f32x4 s4 = {scl[0], scl[1], scl[2], scl[3]};
        *(f32x4*)&rowscale[16 * w + 4 * g] = s4;
      }
    }

    // ---- P = 2^(S - mold), trunc to bf16 ----
#pragma unroll
    for (int j = 0; j < 4; ++j)
#pragma unroll
      for (int r = 0; r < 4; ++r) {
        float e = exp2f(sacc[j][r] - mold[r]);
        Pt[(16 * w + 4 * g + r) * 72 + 16 * j + c] = f2b_trunc(e);
      }
    __syncthreads();                       // b2: Pt + rowscale visible

    if (!ok) {
#pragma unroll
      for (int i = 0; i < 4; ++i) {
        f32x4 s4 = *(const f32x4*)&rowscale[16 * i + 4 * g];
#pragma unroll
        for (int t = 0; t < 4; ++t) {
          oacc[i][t][0] *= s4[0]; oacc[i][t][1] *= s4[1];
          oacc[i][t][2] *= s4[2]; oacc[i][t][3] *= s4[3];
        }
        sumacc[i][0] *= s4[0]; sumacc[i][1] *= s4[1];
        sumacc[i][2] *= s4[2]; sumacc[i][3] *= s4[3];
      }
    }

    // ---- PV + row-sum-via-ones (G from prefetched regs) ----
#pragma unroll
    for (int s2 = 0; s2 < 2; ++s2) {
      bhalf8 pa[4];
#pragma unroll
      for (int i = 0; i < 4; ++i)
        pa[i] = *(const bhalf8*)((const char*)Pt +
                                 (16 * i + c) * 144 + 16 * g + 64 * s2);
#pragma unroll
      for (int t = 0; t < 4; ++t)
#pragma unroll
        for (int i = 0; i < 4; ++i)
          oacc[i][t] = __builtin_amdgcn_mfma_f32_16x16x32_bf16(pa[i], gcur[s2][t], oacc[i][t], 0, 0, 0);
#pragma unroll
      for (int i = 0; i < 4; ++i)
        sumacc[i] = __builtin_amdgcn_mfma_f32_16x16x32_bf16(pa[i], ones, sumacc[i], 0, 0, 0);
    }

    if (mb < 31) {
#pragma unroll
      for (int s2 = 0; s2 < 2; ++s2)
#pragma unroll
        for (int t = 0; t < 4; ++t)
          gcur[s2][t] = gnxt[s2][t];
    }
  }

  // ---- epilogue: qcb = bf16(qcb + O / rowsum) ----
  long qbase = ((long)b * SOUT + nb * 64) * 256;
#pragma unroll
  for (int i = 0; i < 4; ++i) {
#pragma unroll
    for (int r = 0; r < 4; ++r) {
      float inv = 1.0f / sumacc[i][r];
      long rb = qbase + (long)(16 * i + 4 * g + r) * 256 + 64 * w + c;
#pragma unroll
      for (int t = 0; t < 4; ++t) {
        float val = b2f(qcb[rb + 16 * t]) + oacc[i][t][r] * inv;
        qcb[rb + 16 * t] = f2b(val);
      }
    }
  }
}

// ---------------------------------------------------------------------------
extern "C" void kernel_launch(void* const* d_in, const int* in_sizes, int n_in,
                              void* d_out, int out_size, void* d_ws, size_t ws_size,
                              hipStream_t stream) {
  (void)in_sizes; (void)n_in; (void)out_size; (void)ws_size;
  const float* p   = (const float*)d_in[0];
  const float* Wh  = (const float*)d_in[1];
  const float* bh  = (const float*)d_in[2];
  const float* Wl  = (const float*)d_in[3];
  const float* bl  = (const float*)d_in[4];
  const float* Wg  = (const float*)d_in[5];
  const float* bg  = (const float*)d_in[6];
  const float* Wf  = (const float*)d_in[7];
  const float* bf  = (const float*)d_in[8];
  const float* Wup = (const float*)d_in[9];
  const float* bup = (const float*)d_in[10];
  const float* Wd1 = (const float*)d_in[11];
  const float* bd1 = (const float*)d_in[12];
  const float* Wd2 = (const float*)d_in[13];
  const float* bd2 = (const float*)d_in[14];
  const int* mArr  = (const int*)d_in[15];
  const int* nArr  = (const int*)d_in[16];
  float* out = (float*)d_out;

  // workspace layout
  float* ws    = (float*)d_ws;
  float* pts   = ws;                        // 4096 f32
  float* p1    = ws + 4096;                 // 8,388,608 f32
  float* pm    = p1 + 8388608;              // 2,097,152 f32
  float* bhl   = pm + 2097152;              // 128 f32
  ushort* qcb  = (ushort*)(bhl + 128);      // 16,777,216 us
  ushort* hlb  = qcb + 16777216;            //  8,388,608 us ([b][2048][128])
  ushort* gt   = hlb + 8388608;             // 16,777,216 us
  ushort* p1b  = gt + 16777216;             //  8,388,608 us
  ushort* d1b  = p1b + 8388608;             //  4,194,304 us
  ushort* wts  = d1b + 4194304;             //    294,912 us
  ushort* Whlt = wts;                       // Wht(16384) ++ Wlt(16384) contiguous
  ushort* Wgt  = wts + 32768;
  ushort* Wft  = wts + 98304;
  ushort* Wd1t = wts + 131072;
  ushort* Wd2t = wts + 262144;

  pts_kernel<<<8, 256, 0, stream>>>(mArr, nArr, pts);
  wconv_kernel<<<dim3(512, 7), 256, 0, stream>>>(Wh, Wl, Wg, Wf, Wd1, Wd2, bh, bl, wts, bhl);

  // ---------------- up #1 ----------------
  qc_kernel<<<4096, 128, 0, stream>>>(p, pts, Wup, bup, qcb);
  mgemm<5><<<dim3(2, 512), 256, 0, stream>>>(qcb, Whlt, bhl, hlb, nullptr, nullptr, 65536, 128, 256);
  mgemm<1><<<dim3(4, 512), 256, 0, stream>>>(qcb, Wgt, bg, gt, nullptr, nullptr, 65536, 256, 256);
  attn_kernel<<<1024, 256, 0, stream>>>(hlb, gt, qcb);
  mgemm<2><<<dim3(2, 512), 256, 0, stream>>>(qcb, Wft, bf, p1b, p1, nullptr, 65536, 128, 256);

  // ---------------- down ----------------
  mgemm<0><<<dim3(4, 128), 256, 0, stream>>>(p1b, Wd1t, bd1, d1b, nullptr, nullptr, 16384, 256, 512);
  mgemm<3><<<dim3(2, 128), 256, 0, stream>>>(d1b, Wd2t, bd2, pm, nullptr, p, 16384, 128, 256);

  // ---------------- up #2 + final add ----------------
  qc_kernel<<<4096, 128, 0, stream>>>(pm, pts, Wup, bup, qcb);
  mgemm<5><<<dim3(2, 512), 256, 0, stream>>>(qcb, Whlt, bhl, hlb, nullptr, nullptr, 65536, 128, 256);
  mgemm<1><<<dim3(4, 512), 256, 0, stream>>>(qcb, Wgt, bg, gt, nullptr, nullptr, 65536, 256, 256);
  attn_kernel<<<1024, 256, 0, stream>>>(hlb, gt, qcb);
  mgemm<4><<<dim3(2, 512), 256, 0, stream>>>(qcb, Wft, bf, out, nullptr, p1, 65536, 128, 256);
}

// Round 6
// 771.332 us; speedup vs baseline: 1.1357x; 1.1357x over previous
//
#include <hip/hip_runtime.h>
#include <hip/hip_bf16.h>
#include <cmath>

#define NB   32
#define SOUT 2048
#define SIN  512
#define LOG2E 1.4426950408889634f

typedef __attribute__((ext_vector_type(8))) short bhalf8;   // 8 bf16 (4 VGPRs)
typedef __attribute__((ext_vector_type(4))) float f32x4;

__device__ inline ushort f2b(float x) {                     // f32 -> bf16 RNE
  union { float f; unsigned u; } v; v.f = x;
  unsigned r = v.u + 0x7FFFu + ((v.u >> 16) & 1u);
  return (ushort)(r >> 16);
}
__device__ inline ushort f2b_trunc(float x) {               // f32 -> bf16 trunc (x>0)
  union { float f; unsigned u; } v; v.f = x;
  return (ushort)(v.u >> 16);
}
__device__ inline float b2f(ushort u) {
  union { unsigned u; float f; } v; v.u = ((unsigned)u) << 16;
  return v.f;
}

__device__ inline void gload16(const void* g, void* l) {    // async global->LDS, 16B/lane
  __builtin_amdgcn_global_load_lds(
      (const __attribute__((address_space(1))) void*)g,
      (__attribute__((address_space(3))) void*)l, 16, 0, 0);
}

// ---------------------------------------------------------------------------
// pts
// ---------------------------------------------------------------------------
__global__ void pts_kernel(const int* __restrict__ mArr, const int* __restrict__ nArr,
                           float* __restrict__ pts) {
  int k = blockIdx.x * blockDim.x + threadIdx.x;
  if (k >= SOUT) return;
  int m = mArr[0], n = nArr[0];
  int b = k % m, a = k / m;
  int ixb = (int)rint(45.0 * (double)b / (double)(m - 1));
  int iya = (int)rint(45.0 * (double)a / (double)(n - 1));
  const float step = 0.6f / 45.0f;
  pts[2 * k + 0] = -0.3f + step * (float)iya;
  pts[2 * k + 1] = -0.3f + step * (float)ixb;
}

// ---------------------------------------------------------------------------
// wconv: transpose-convert weights W[K,N] f32 -> Wt[N,K] bf16; which==6 builds
// the concatenated h|l bias (float).
// ---------------------------------------------------------------------------
__global__ __launch_bounds__(256) void wconv_kernel(
    const float* __restrict__ Wh, const float* __restrict__ Wl,
    const float* __restrict__ Wg, const float* __restrict__ Wf,
    const float* __restrict__ Wd1, const float* __restrict__ Wd2,
    const float* __restrict__ bh, const float* __restrict__ bl,
    ushort* __restrict__ dst, float* __restrict__ fbias) {
  const int which = blockIdx.y;
  if (which == 6) {
    int idx = blockIdx.x * 256 + threadIdx.x;
    if (idx < 128) fbias[idx] = idx < 64 ? bh[idx] : bl[idx - 64];
    return;
  }
  const float* src; int K, N; long off;
  switch (which) {
    case 0: src = Wh;  K = 256; N = 64;  off = 0;      break;
    case 1: src = Wl;  K = 256; N = 64;  off = 16384;  break;
    case 2: src = Wg;  K = 256; N = 256; off = 32768;  break;
    case 3: src = Wf;  K = 256; N = 128; off = 98304;  break;
    case 4: src = Wd1; K = 512; N = 256; off = 131072; break;
    default:src = Wd2; K = 256; N = 128; off = 262144; break;
  }
  int idx = blockIdx.x * 256 + threadIdx.x;
  if (idx >= K * N) return;
  int n = idx / K, k = idx - n * K;
  dst[off + idx] = f2b(src[(long)k * N + n]);
}

// ---------------------------------------------------------------------------
// qc builder -> qcb bf16 only
// ---------------------------------------------------------------------------
__global__ __launch_bounds__(128) void qc_kernel(
    const float* __restrict__ q, const float* __restrict__ pts,
    const float* __restrict__ Wup, const float* __restrict__ bup,
    ushort* __restrict__ qcb) {
  __shared__ float xs[16][132];
  int tid = threadIdx.x;
  long row0 = (long)blockIdx.x * 16;
  for (int r = 0; r < 16; ++r) {
    long row = row0 + r;
    int b = (int)(row >> 11);
    int i = (int)(row & 2047);
    xs[r][tid] = q[((long)b * SIN + (i & 511)) * 128 + tid];
    if (tid < 2) xs[r][128 + tid] = pts[2 * i + tid];
  }
  __syncthreads();
  float acc[16];
#pragma unroll
  for (int r = 0; r < 16; ++r) acc[r] = 0.f;
  for (int k = 0; k < 130; ++k) {
    float w = Wup[k * 128 + tid];
#pragma unroll
    for (int r = 0; r < 16; ++r) acc[r] += xs[r][k] * w;
  }
  float bb = bup[tid];
#pragma unroll
  for (int r = 0; r < 16; ++r) {
    long row = row0 + r;
    qcb[row * 256 + tid] = f2b(xs[r][tid]);
    qcb[row * 256 + 128 + tid] = f2b(fmaxf(acc[r] + bb, 0.f));
  }
}

// ---------------------------------------------------------------------------
// MFMA bf16 GEMM: acc = A[M,K] @ Wt[N,K]^T + bias, relu, epilogue by MODE.
//   MODE 0: bf16 row-major out
//   MODE 1: bf16 per-batch transposed gt [b][256][2048]
//   MODE 2: f32 out2 + bf16 outv
//   MODE 3: f32 outv = aux - relu(acc)
//   MODE 4: f32 outv = relu(acc) + aux
//   MODE 5: bf16 row-major out (N=128), cols>=64 scaled by LOG2E  (h|l merged)
// ---------------------------------------------------------------------------
template <int MODE>
__global__ __launch_bounds__(256) void mgemm(
    const ushort* __restrict__ A, const ushort* __restrict__ Wt,
    const float* __restrict__ bias, void* __restrict__ outv,
    float* __restrict__ out2, const float* __restrict__ aux,
    int M, int N, int K) {
  __shared__ alignas(16) ushort As[128 * 64];
  __shared__ alignas(16) ushort Bs[64 * 64];
  const int tid = threadIdx.x;
  const int w = tid >> 6, lane = tid & 63, g = lane >> 4, c = lane & 15;
  const int wm = w >> 1, wn = w & 1;
  const long row0 = (long)blockIdx.y * 128;
  const int col0 = blockIdx.x * 64;
  const long Astride = (long)K * 2;
  const char* Ab = (const char*)A;
  const char* Wb = (const char*)Wt;

  f32x4 acc[4][2];
#pragma unroll
  for (int i = 0; i < 4; ++i)
#pragma unroll
    for (int j = 0; j < 2; ++j) acc[i][j] = (f32x4){0.f, 0.f, 0.f, 0.f};

  for (int k0 = 0; k0 < K; k0 += 64) {
#pragma unroll
    for (int it = 0; it < 4; ++it) {
      int o = it * 4096 + w * 1024 + lane * 16;
      int row = o >> 7, cb = o & 127;
      gload16(Ab + (row0 + row) * Astride + k0 * 2 + (cb ^ ((row & 7) << 4)),
              (char*)As + it * 4096 + w * 1024);
    }
#pragma unroll
    for (int it = 0; it < 2; ++it) {
      int o = it * 4096 + w * 1024 + lane * 16;
      int row = o >> 7, cb = o & 127;
      gload16(Wb + (long)(col0 + row) * Astride + k0 * 2 + (cb ^ ((row & 7) << 4)),
              (char*)Bs + it * 4096 + w * 1024);
    }
    __syncthreads();
#pragma unroll
    for (int koff = 0; koff < 2; ++koff) {
      bhalf8 a[4], bfr[2];
#pragma unroll
      for (int mi = 0; mi < 4; ++mi) {
        int row = 64 * wm + 16 * mi + c;
        a[mi] = *(const bhalf8*)((const char*)As + row * 128 +
                                 ((16 * g + 64 * koff) ^ ((row & 7) << 4)));
      }
#pragma unroll
      for (int ni = 0; ni < 2; ++ni) {
        int row = 32 * wn + 16 * ni + c;
        bfr[ni] = *(const bhalf8*)((const char*)Bs + row * 128 +
                                   ((16 * g + 64 * koff) ^ ((row & 7) << 4)));
      }
#pragma unroll
      for (int mi = 0; mi < 4; ++mi)
#pragma unroll
        for (int ni = 0; ni < 2; ++ni)
          acc[mi][ni] = __builtin_amdgcn_mfma_f32_16x16x32_bf16(a[mi], bfr[ni], acc[mi][ni], 0, 0, 0);
    }
    __syncthreads();
  }

#pragma unroll
  for (int ni = 0; ni < 2; ++ni) {
    int n = col0 + 32 * wn + 16 * ni + c;
    float bn = bias[n];
#pragma unroll
    for (int mi = 0; mi < 4; ++mi) {
      long m0 = row0 + 64 * wm + 16 * mi + 4 * g;
      float v[4];
#pragma unroll
      for (int r = 0; r < 4; ++r) v[r] = fmaxf(acc[mi][ni][r] + bn, 0.f);
      if (MODE == 0) {
        ushort* O = (ushort*)outv;
#pragma unroll
        for (int r = 0; r < 4; ++r) O[(m0 + r) * N + n] = f2b(v[r]);
      } else if (MODE == 5) {
        ushort* O = (ushort*)outv;
        float sc = (n >= 64) ? LOG2E : 1.0f;
#pragma unroll
        for (int r = 0; r < 4; ++r) O[(m0 + r) * 128 + n] = f2b(v[r] * sc);
      } else if (MODE == 1) {
        int bb = (int)(m0 >> 11);
        int ml = (int)(m0 & 2047);
        ushort4 u4;
        u4.x = f2b(v[0]); u4.y = f2b(v[1]); u4.z = f2b(v[2]); u4.w = f2b(v[3]);
        *(ushort4*)((ushort*)outv + ((long)bb * 256 + n) * 2048 + ml) = u4;
      } else if (MODE == 2) {
        ushort* O = (ushort*)outv;
#pragma unroll
        for (int r = 0; r < 4; ++r) {
          out2[(m0 + r) * N + n] = v[r];
          O[(m0 + r) * N + n] = f2b(v[r]);
        }
      } else if (MODE == 3) {
        float* O = (float*)outv;
#pragma unroll
        for (int r = 0; r < 4; ++r) O[(m0 + r) * N + n] = aux[(m0 + r) * N + n] - v[r];
      } else {
        float* O = (float*)outv;
#pragma unroll
        for (int r = 0; r < 4; ++r) O[(m0 + r) * N + n] = v[r] + aux[(m0 + r) * N + n];
      }
    }
  }
}

// ---------------------------------------------------------------------------
// MFMA flash attention v6 (single-barrier iteration):
//   qcb[b,n,:] = bf16( qcb[b,n,:] + softmax_m(l[n]·h[m]) @ g )
// hl bf16 [b][2048][128] (cols 0:64=h, 64:128=l*log2e); gt bf16 [b][256][2048].
// Pt/rowscale/okf double-buffered -> one __syncthreads per kv-iter.
// H loads first, then G(s2=0) (vmcnt FIFO: QK waits only for H; G drains at
// the barrier, hidden under QK+softmax). G(s2=1) loads after the barrier.
// Per-row defer-max; block vote only gates the O-rescale multiply.
// ---------------------------------------------------------------------------
__global__ __launch_bounds__(256) void attn_kernel(
    const ushort* __restrict__ hl, const ushort* __restrict__ gtm,
    ushort* __restrict__ qcb) {
  __shared__ alignas(16) ushort Pt[2][64 * 72];
  __shared__ alignas(16) float rowscale[2][64];
  __shared__ int okf[2][4];

  const int tid = threadIdx.x;
  const int w = tid >> 6, lane = tid & 63, g = lane >> 4, c = lane & 15;
  const int bid = blockIdx.x;
  const int wg = (bid & 7) * 128 + (bid >> 3);   // XCD-contiguous remap (1024%8==0)
  const int b = wg >> 5, nb = wg & 31;
  const float THR = 11.0f;                        // log2 units

  // L (query, pre-scaled) fragments: rows 16w+c, k = 8g + 32s, cols 64..127
  const ushort* lrow = hl + ((long)b * SOUT + nb * 64 + 16 * w + c) * 128 + 64 + 8 * g;
  bhalf8 la[2];
  la[0] = *(const bhalf8*)(lrow);
  la[1] = *(const bhalf8*)(lrow + 32);

  bhalf8 ones;
#pragma unroll
  for (int i = 0; i < 8; ++i) ones[i] = (short)0x3F80;      // bf16 1.0

  float mold[4];
#pragma unroll
  for (int r = 0; r < 4; ++r) mold[r] = -INFINITY;
  f32x4 oacc[4][4], sumacc[4];
#pragma unroll
  for (int i = 0; i < 4; ++i) {
    sumacc[i] = (f32x4){0.f, 0.f, 0.f, 0.f};
#pragma unroll
    for (int t = 0; t < 4; ++t) oacc[i][t] = (f32x4){0.f, 0.f, 0.f, 0.f};
  }

  const ushort* hbase0 = hl + ((long)b * SOUT + c) * 128 + 8 * g;
  const ushort* gbase0 = gtm + ((long)b * 256 + 64 * w + c) * 2048 + 8 * g;

  for (int mb = 0; mb < 32; ++mb) {
    const int buf = mb & 1;
    ushort* PtB = Pt[buf];

    // ---- H fragment loads (oldest in vmcnt FIFO -> QK waits only these) ----
    const ushort* hrow = hbase0 + (long)mb * 64 * 128;
    bhalf8 hb[4][2];
#pragma unroll
    for (int j = 0; j < 4; ++j)
#pragma unroll
      for (int s = 0; s < 2; ++s)
        hb[j][s] = *(const bhalf8*)(hrow + j * 16 * 128 + s * 32);

    // ---- G(s2=0) fragment loads: consumed after the barrier ----
    const ushort* gn = gbase0 + mb * 64;
    bhalf8 gb0[4];
#pragma unroll
    for (int t = 0; t < 4; ++t)
      gb0[t] = *(const bhalf8*)(gn + (long)t * 16 * 2048);

    // ---- QK^T (log2-domain scores) ----
    f32x4 sacc[4];
#pragma unroll
    for (int j = 0; j < 4; ++j) sacc[j] = (f32x4){0.f, 0.f, 0.f, 0.f};
#pragma unroll
    for (int j = 0; j < 4; ++j)
#pragma unroll
      for (int s = 0; s < 2; ++s)
        sacc[j] = __builtin_amdgcn_mfma_f32_16x16x32_bf16(la[s], hb[j][s], sacc[j], 0, 0, 0);

    // ---- per-row online softmax with defer-max ----
    float mloc[4], mnew[4], scl[4];
#pragma unroll
    for (int r = 0; r < 4; ++r)
      mloc[r] = fmaxf(fmaxf(sacc[0][r], sacc[1][r]), fmaxf(sacc[2][r], sacc[3][r]));
#pragma unroll
    for (int off = 1; off < 16; off <<= 1)
#pragma unroll
      for (int r = 0; r < 4; ++r)
        mloc[r] = fmaxf(mloc[r], __shfl_xor(mloc[r], off));
    int okl = 1;
#pragma unroll
    for (int r = 0; r < 4; ++r) {
      mnew[r] = fmaxf(mold[r], mloc[r]);
      int keep = (mloc[r] <= mold[r] + THR) ? 1 : 0;
      float ns = exp2f(mold[r] - mnew[r]);   // first iter: exp2(-inf)=0
      scl[r] = keep ? 1.0f : ns;
      mold[r] = keep ? mold[r] : mnew[r];
      okl &= keep;
    }
    int okw = __all(okl);
    if (lane == 0) okf[buf][w] = okw;

    // ---- P = 2^(S - mold), trunc to bf16 ----
#pragma unroll
    for (int j = 0; j < 4; ++j)
#pragma unroll
      for (int r = 0; r < 4; ++r) {
        float e = exp2f(sacc[j][r] - mold[r]);
        PtB[(16 * w + 4 * g + r) * 72 + 16 * j + c] = f2b_trunc(e);
      }
    if (c == 0) {
      f32x4 s4 = {scl[0], scl[1], scl[2], scl[3]};
      *(f32x4*)&rowscale[buf][16 * w + 4 * g] = s4;
    }
    __syncthreads();   // single barrier: Pt/rowscale/okf visible; drains G(s2=0)

    // ---- G(s2=1) fragment loads (covered by rescale + PV s2=0) ----
    bhalf8 gb1[4];
#pragma unroll
    for (int t = 0; t < 4; ++t)
      gb1[t] = *(const bhalf8*)(gn + (long)t * 16 * 2048 + 32);

    int ok = okf[buf][0] & okf[buf][1] & okf[buf][2] & okf[buf][3];
    if (!ok) {
#pragma unroll
      for (int i = 0; i < 4; ++i) {
        f32x4 s4 = *(const f32x4*)&rowscale[buf][16 * i + 4 * g];
#pragma unroll
        for (int t = 0; t < 4; ++t) {
          oacc[i][t][0] *= s4[0]; oacc[i][t][1] *= s4[1];
          oacc[i][t][2] *= s4[2]; oacc[i][t][3] *= s4[3];
        }
        sumacc[i][0] *= s4[0]; sumacc[i][1] *= s4[1];
        sumacc[i][2] *= s4[2]; sumacc[i][3] *= s4[3];
      }
    }

    // ---- PV s2=0 ----
    {
      bhalf8 pa[4];
#pragma unroll
      for (int i = 0; i < 4; ++i)
        pa[i] = *(const bhalf8*)((const char*)PtB + (16 * i + c) * 144 + 16 * g);
#pragma unroll
      for (int t = 0; t < 4; ++t)
#pragma unroll
        for (int i = 0; i < 4; ++i)
          oacc[i][t] = __builtin_amdgcn_mfma_f32_16x16x32_bf16(pa[i], gb0[t], oacc[i][t], 0, 0, 0);
#pragma unroll
      for (int i = 0; i < 4; ++i)
        sumacc[i] = __builtin_amdgcn_mfma_f32_16x16x32_bf16(pa[i], ones, sumacc[i], 0, 0, 0);
    }
    // ---- PV s2=1 ----
    {
      bhalf8 pa[4];
#pragma unroll
      for (int i = 0; i < 4; ++i)
        pa[i] = *(const bhalf8*)((const char*)PtB + (16 * i + c) * 144 + 16 * g + 64);
#pragma unroll
      for (int t = 0; t < 4; ++t)
#pragma unroll
        for (int i = 0; i < 4; ++i)
          oacc[i][t] = __builtin_amdgcn_mfma_f32_16x16x32_bf16(pa[i], gb1[t], oacc[i][t], 0, 0, 0);
#pragma unroll
      for (int i = 0; i < 4; ++i)
        sumacc[i] = __builtin_amdgcn_mfma_f32_16x16x32_bf16(pa[i], ones, sumacc[i], 0, 0, 0);
    }
  }

  // ---- epilogue: qcb = bf16(qcb + O / rowsum) ----
  long qbase = ((long)b * SOUT + nb * 64) * 256;
#pragma unroll
  for (int i = 0; i < 4; ++i) {
#pragma unroll
    for (int r = 0; r < 4; ++r) {
      float inv = 1.0f / sumacc[i][r];
      long rb = qbase + (long)(16 * i + 4 * g + r) * 256 + 64 * w + c;
#pragma unroll
      for (int t = 0; t < 4; ++t) {
        float val = b2f(qcb[rb + 16 * t]) + oacc[i][t][r] * inv;
        qcb[rb + 16 * t] = f2b(val);
      }
    }
  }
}

// ---------------------------------------------------------------------------
extern "C" void kernel_launch(void* const* d_in, const int* in_sizes, int n_in,
                              void* d_out, int out_size, void* d_ws, size_t ws_size,
                              hipStream_t stream) {
  (void)in_sizes; (void)n_in; (void)out_size; (void)ws_size;
  const float* p   = (const float*)d_in[0];
  const float* Wh  = (const float*)d_in[1];
  const float* bh  = (const float*)d_in[2];
  const float* Wl  = (const float*)d_in[3];
  const float* bl  = (const float*)d_in[4];
  const float* Wg  = (const float*)d_in[5];
  const float* bg  = (const float*)d_in[6];
  const float* Wf  = (const float*)d_in[7];
  const float* bf  = (const float*)d_in[8];
  const float* Wup = (const float*)d_in[9];
  const float* bup = (const float*)d_in[10];
  const float* Wd1 = (const float*)d_in[11];
  const float* bd1 = (const float*)d_in[12];
  const float* Wd2 = (const float*)d_in[13];
  const float* bd2 = (const float*)d_in[14];
  const int* mArr  = (const int*)d_in[15];
  const int* nArr  = (const int*)d_in[16];
  float* out = (float*)d_out;

  // workspace layout
  float* ws    = (float*)d_ws;
  float* pts   = ws;                        // 4096 f32
  float* p1    = ws + 4096;                 // 8,388,608 f32
  float* pm    = p1 + 8388608;              // 2,097,152 f32
  float* bhl   = pm + 2097152;              // 128 f32
  ushort* qcb  = (ushort*)(bhl + 128);      // 16,777,216 us
  ushort* hlb  = qcb + 16777216;            //  8,388,608 us ([b][2048][128])
  ushort* gt   = hlb + 8388608;             // 16,777,216 us
  ushort* p1b  = gt + 16777216;             //  8,388,608 us
  ushort* d1b  = p1b + 8388608;             //  4,194,304 us
  ushort* wts  = d1b + 4194304;             //    294,912 us
  ushort* Whlt = wts;                       // Wht(16384) ++ Wlt(16384) contiguous
  ushort* Wgt  = wts + 32768;
  ushort* Wft  = wts + 98304;
  ushort* Wd1t = wts + 131072;
  ushort* Wd2t = wts + 262144;

  pts_kernel<<<8, 256, 0, stream>>>(mArr, nArr, pts);
  wconv_kernel<<<dim3(512, 7), 256, 0, stream>>>(Wh, Wl, Wg, Wf, Wd1, Wd2, bh, bl, wts, bhl);

  // ---------------- up #1 ----------------
  qc_kernel<<<4096, 128, 0, stream>>>(p, pts, Wup, bup, qcb);
  mgemm<5><<<dim3(2, 512), 256, 0, stream>>>(qcb, Whlt, bhl, hlb, nullptr, nullptr, 65536, 128, 256);
  mgemm<1><<<dim3(4, 512), 256, 0, stream>>>(qcb, Wgt, bg, gt, nullptr, nullptr, 65536, 256, 256);
  attn_kernel<<<1024, 256, 0, stream>>>(hlb, gt, qcb);
  mgemm<2><<<dim3(2, 512), 256, 0, stream>>>(qcb, Wft, bf, p1b, p1, nullptr, 65536, 128, 256);

  // ---------------- down ----------------
  mgemm<0><<<dim3(4, 128), 256, 0, stream>>>(p1b, Wd1t, bd1, d1b, nullptr, nullptr, 16384, 256, 512);
  mgemm<3><<<dim3(2, 128), 256, 0, stream>>>(d1b, Wd2t, bd2, pm, nullptr, p, 16384, 128, 256);

  // ---------------- up #2 + final add ----------------
  qc_kernel<<<4096, 128, 0, stream>>>(pm, pts, Wup, bup, qcb);
  mgemm<5><<<dim3(2, 512), 256, 0, stream>>>(qcb, Whlt, bhl, hlb, nullptr, nullptr, 65536, 128, 256);
  mgemm<1><<<dim3(4, 512), 256, 0, stream>>>(qcb, Wgt, bg, gt, nullptr, nullptr, 65536, 256, 256);
  attn_kernel<<<1024, 256, 0, stream>>>(hlb, gt, qcb);
  mgemm<4><<<dim3(2, 512), 256, 0, stream>>>(qcb, Wft, bf, out, nullptr, p1, 65536, 128, 256);
}